// Round 8
// baseline (1150.240 us; speedup 1.0000x reference)
//
#include <hip/hip_runtime.h>
#include <stdint.h>

typedef unsigned short v2u   __attribute__((ext_vector_type(2)));
typedef unsigned short u16x8 __attribute__((ext_vector_type(8)));
typedef short          s16x8 __attribute__((ext_vector_type(8)));
typedef float          f32x4 __attribute__((ext_vector_type(4)));

#define TM 32
#define TN 32
#define BK 32

__device__ __forceinline__ uint32_t rnd_bf16(float f) {
    uint32_t u = __builtin_bit_cast(uint32_t, f);
    return (u + 0x7FFFu + ((u >> 16) & 1u)) >> 16;   // RNE f32 -> bf16 (finite)
}
__device__ __forceinline__ float bf16_to_f32(uint32_t bits16) {
    return __builtin_bit_cast(float, bits16 << 16);
}

// HW-validated pack transforms (r12/r15): mag floored at 0x2000;
// X side folds (sign - 0x3F80), W side keeps sign|mag.
__device__ __forceinline__ uint32_t pack_x(uint32_t w0, uint32_t w1) {
    uint32_t u = (w0 >> 16) | (w1 & 0xFFFF0000u);
    const v2u vfloor = {0x2000, 0x2000};
    v2u m = __builtin_bit_cast(v2u, u & 0x7FFF7FFFu);
    m = __builtin_elementwise_max(m, vfloor);
    uint32_t c = (u & 0x80008000u) ^ 0xC080C080u;    // sign - 0x3F80
    v2u xp = m + __builtin_bit_cast(v2u, c);
    return __builtin_bit_cast(uint32_t, xp);
}
__device__ __forceinline__ uint32_t pack_w(uint32_t w0, uint32_t w1) {
    uint32_t v = (w0 >> 16) | (w1 & 0xFFFF0000u);
    const v2u vfloor = {0x2000, 0x2000};
    v2u m = __builtin_bit_cast(v2u, v & 0x7FFF7FFFu);
    m = __builtin_elementwise_max(m, vfloor);
    return __builtin_bit_cast(uint32_t, m) | (v & 0x80008000u);
}

// ROUND 20. r17/r19 invariant at ~570-585 us across occupancy/barrier/
// setprio changes -> the LOCKSTEP is the limiter (m233: in a barrier-synced
// 2-phase loop, no single tweak helps; all waves demand LDS together then
// MFMA together -> phase-aligned pipe idling). This round: 1 wave per block
// (64 thr), 32x32 tile/wave (= r17's per-wave work, wm=wn=0; all validated
// mapping formulas unchanged), private 8 KiB dbuf LDS, ZERO barriers (all
// LDS deps wave-local; compiler lgkmcnt handles RAW). ~12 independent waves
// /CU at uncorrelated phases keep MFMA+LDS+VALU pipes fed (m114 regime).
// Staging redundancy x2.67 is cheap (L1/L2 13 TB/s agg << ceilings).
__global__ __launch_bounds__(64, 3)
void fpma_gemm(const uint32_t* __restrict__ X,   // [M,K] f32 bits (bf16-exact)
               const uint32_t* __restrict__ Wt,  // [N,K] f32 bits (bf16-exact)
               const float*    __restrict__ Bias,// [N]   f32 (bf16-exact)
               float* __restrict__ Out,          // [M,N] f32 (bf16-valued)
               int M, int N, int K)
{
    __shared__ uint32_t Xp[2][32 * 16];  // [buf][row][16 packed], oct-swizzled
    __shared__ uint32_t Wp[2][32 * 16];

    const int lane = threadIdx.x & 63;
    const int m0 = blockIdx.y * TM;
    const int n0 = blockIdx.x * TN;

    // compute-side roles (r15/r16-validated A/D mapping)
    const int cc = lane & 15;
    const int q  = lane >> 4;            // k-octet
    const int mi = cc >> 2;
    const int ni = cc & 3;

    const int xrd = mi * 16 + ((q ^ mi) << 2);       // + a*64 -> row 4a+mi
    int wrd[4];
    #pragma unroll
    for (int t = 0; t < 4; ++t)                      // row 16bg+4((q+t)&3)+ni
        wrd[t] = ni * 16 + ((q ^ ni) << 2) + (((q + t) & 3) << 6);

    // B selectors: ones iff D col-group (cc>>2) == (q+t)&3
    u16x8 bt[4];
    #pragma unroll
    for (int t = 0; t < 4; ++t) {
        unsigned short v = ((cc >> 2) == ((q + t) & 3)) ? (unsigned short)0x3F80
                                                        : (unsigned short)0;
        bt[t] = (u16x8){v, v, v, v, v, v, v, v};
    }

    // staging roles: lane -> (row sr = lane>>1, k-half sh = lane&1).
    // Stages raw words sh*16..+15 of its row for X and W: pack to octets
    // o = 2sh, 2sh+1, stored at swizzled octet position o ^ (sr&3).
    const int sr = lane >> 1;
    const int sh = lane & 1;
    const uint32_t* xptr = X  + (size_t)(m0 + sr) * K + sh * 16;
    const uint32_t* wptr = Wt + (size_t)(n0 + sr) * K + sh * 16;
    const int st1 = sr * 16 + (((2 * sh)     ^ (sr & 3)) << 2);
    const int st2 = sr * 16 + (((2 * sh + 1) ^ (sr & 3)) << 2);

    f32x4 acc[8][2];
    #pragma unroll
    for (int a = 0; a < 8; ++a)
        #pragma unroll
        for (int bg = 0; bg < 2; ++bg) acc[a][bg] = (f32x4){0.f, 0.f, 0.f, 0.f};

    // prologue: stage chunk 0 directly
    {
        uint4 a0 = *(const uint4*)(xptr),     a1 = *(const uint4*)(xptr + 4);
        uint4 a2 = *(const uint4*)(xptr + 8), a3 = *(const uint4*)(xptr + 12);
        uint4 b0 = *(const uint4*)(wptr),     b1 = *(const uint4*)(wptr + 4);
        uint4 b2 = *(const uint4*)(wptr + 8), b3 = *(const uint4*)(wptr + 12);
        *(uint4*)&Xp[0][st1] = (uint4){pack_x(a0.x,a0.y), pack_x(a0.z,a0.w),
                                       pack_x(a1.x,a1.y), pack_x(a1.z,a1.w)};
        *(uint4*)&Xp[0][st2] = (uint4){pack_x(a2.x,a2.y), pack_x(a2.z,a2.w),
                                       pack_x(a3.x,a3.y), pack_x(a3.z,a3.w)};
        *(uint4*)&Wp[0][st1] = (uint4){pack_w(b0.x,b0.y), pack_w(b0.z,b0.w),
                                       pack_w(b1.x,b1.y), pack_w(b1.z,b1.w)};
        *(uint4*)&Wp[0][st2] = (uint4){pack_w(b2.x,b2.y), pack_w(b2.z,b2.w),
                                       pack_w(b3.x,b3.y), pack_w(b3.z,b3.w)};
    }
    // prefetch chunk 1 into regs (8 uint4 in flight)
    uint4 gx0={0,0,0,0}, gx1={0,0,0,0}, gx2={0,0,0,0}, gx3={0,0,0,0};
    uint4 gw0={0,0,0,0}, gw1={0,0,0,0}, gw2={0,0,0,0}, gw3={0,0,0,0};
    const int ksteps = K / BK;
    if (ksteps > 1) {
        xptr += BK; wptr += BK;
        gx0 = *(const uint4*)(xptr);     gx1 = *(const uint4*)(xptr + 4);
        gx2 = *(const uint4*)(xptr + 8); gx3 = *(const uint4*)(xptr + 12);
        gw0 = *(const uint4*)(wptr);     gw1 = *(const uint4*)(wptr + 4);
        gw2 = *(const uint4*)(wptr + 8); gw3 = *(const uint4*)(wptr + 12);
    }

    #pragma unroll 1
    for (int kt = 0; kt < ksteps; ++kt) {
        const int cur = kt & 1;
        if (kt + 1 < ksteps) {
            // stage chunk kt+1 into other buffer (wave-local; no barrier.
            // Reads of this buffer last chunk precede these writes in
            // program order -> per-wave DS ordering + compiler waits)
            *(uint4*)&Xp[cur^1][st1] = (uint4){pack_x(gx0.x,gx0.y), pack_x(gx0.z,gx0.w),
                                               pack_x(gx1.x,gx1.y), pack_x(gx1.z,gx1.w)};
            *(uint4*)&Xp[cur^1][st2] = (uint4){pack_x(gx2.x,gx2.y), pack_x(gx2.z,gx2.w),
                                               pack_x(gx3.x,gx3.y), pack_x(gx3.z,gx3.w)};
            *(uint4*)&Wp[cur^1][st1] = (uint4){pack_w(gw0.x,gw0.y), pack_w(gw0.z,gw0.w),
                                               pack_w(gw1.x,gw1.y), pack_w(gw1.z,gw1.w)};
            *(uint4*)&Wp[cur^1][st2] = (uint4){pack_w(gw2.x,gw2.y), pack_w(gw2.z,gw2.w),
                                               pack_w(gw3.x,gw3.y), pack_w(gw3.z,gw3.w)};
            if (kt + 2 < ksteps) {       // prefetch chunk kt+2
                xptr += BK; wptr += BK;
                gx0 = *(const uint4*)(xptr);     gx1 = *(const uint4*)(xptr + 4);
                gx2 = *(const uint4*)(xptr + 8); gx3 = *(const uint4*)(xptr + 12);
                gw0 = *(const uint4*)(wptr);     gw1 = *(const uint4*)(wptr + 4);
                gw2 = *(const uint4*)(wptr + 8); gw3 = *(const uint4*)(wptr + 12);
            }
        }

        u16x8 xf[8];
        #pragma unroll
        for (int a = 0; a < 8; ++a)
            xf[a] = __builtin_bit_cast(u16x8,
                        *(const uint4*)&Xp[cur][xrd + a * 64]);

        __builtin_amdgcn_s_setprio(1);
        #pragma unroll
        for (int bg = 0; bg < 2; ++bg) {
            u16x8 wf[4];
            #pragma unroll
            for (int t = 0; t < 4; ++t)
                wf[t] = __builtin_bit_cast(u16x8,
                            *(const uint4*)&Wp[cur][wrd[t] + bg * 256]);
            #pragma unroll
            for (int t = 0; t < 4; ++t)
                #pragma unroll
                for (int a = 0; a < 8; ++a) {
                    u16x8 p = xf[a] + wf[t];           // 4x v_pk_add_u16
                    acc[a][bg] = __builtin_amdgcn_mfma_f32_16x16x32_bf16(
                        __builtin_bit_cast(s16x8, p),
                        __builtin_bit_cast(s16x8, bt[t]),
                        acc[a][bg], 0, 0, 0);
                }
        }
        __builtin_amdgcn_s_setprio(0);
        // no barrier: next iteration's LDS writes are wave-local
    }

    // Epilogue (validated mapping, wm=wn=0). acc[a][bg] at lane (cc,q),
    // elem j = out(m0+4a+q, n0+16bg+4*(cc>>2)+j); lane stores a's with
    // a&3 == cc&3 (disjoint, complete cover of the 32x32 tile).
    const int g = cc >> 2;
    f32x4 bias_[2];
    #pragma unroll
    for (int bg = 0; bg < 2; ++bg)
        bias_[bg] = *(const f32x4*)&Bias[n0 + 16 * bg + 4 * g];

    #pragma unroll
    for (int a = 0; a < 8; ++a) {
        if ((cc & 3) == (a & 3)) {
            #pragma unroll
            for (int bg = 0; bg < 2; ++bg) {
                float o[4];
                #pragma unroll
                for (int j = 0; j < 4; ++j)
                    o[j] = bf16_to_f32(rnd_bf16(
                               bf16_to_f32(rnd_bf16(acc[a][bg][j])) + bias_[bg][j]));
                const size_t row = (size_t)(m0 + 4 * a + q) * N;
                *(float4*)&Out[row + n0 + 16 * bg + 4 * g] =
                    make_float4(o[0], o[1], o[2], o[3]);
            }
        }
    }
}

extern "C" void kernel_launch(void* const* d_in, const int* in_sizes, int n_in,
                              void* d_out, int out_size, void* d_ws, size_t ws_size,
                              hipStream_t stream) {
    (void)n_in; (void)d_ws; (void)ws_size; (void)out_size;
    const uint32_t* X = (const uint32_t*)d_in[0];   // f32 words (bf16-exact)
    const uint32_t* W = (const uint32_t*)d_in[1];
    const float*    B = (const float*)d_in[2];
    float* O = (float*)d_out;                       // f32 out (bf16-valued)

    int N = in_sizes[2];                       // bias [1,N], elements
    int K = (N > 0) ? in_sizes[1] / N : 0;     // weight [N,K]
    int M = (K > 0) ? in_sizes[0] / K : 0;     // input [M,K]
    if (N <= 0 || K <= 0 || M <= 0 ||
        (long long)N * K != (long long)in_sizes[1] ||
        (long long)M * K != (long long)in_sizes[0] ||
        (M % TM) || (N % TN) || (K % BK)) {
        M = 4096; K = 2048; N = 2048;          // documented problem shape
    }

    dim3 grid(N / TN, M / TM);
    fpma_gemm<<<grid, 64, 0, stream>>>(X, W, B, O, M, N, K);
}

// Round 9
// 586.499 us; speedup vs baseline: 1.9612x; 1.9612x over previous
//
#include <hip/hip_runtime.h>
#include <stdint.h>

typedef unsigned short v2u   __attribute__((ext_vector_type(2)));
typedef unsigned short u16x8 __attribute__((ext_vector_type(8)));
typedef short          s16x8 __attribute__((ext_vector_type(8)));
typedef float          f32x4 __attribute__((ext_vector_type(4)));

#define TM 64
#define TN 64
#define BK 32

__device__ __forceinline__ uint32_t rnd_bf16(float f) {
    uint32_t u = __builtin_bit_cast(uint32_t, f);
    return (u + 0x7FFFu + ((u >> 16) & 1u)) >> 16;   // RNE f32 -> bf16 (finite)
}
__device__ __forceinline__ float bf16_to_f32(uint32_t bits16) {
    return __builtin_bit_cast(float, bits16 << 16);
}

// HW-validated pack transforms (r12/r15): mag floored at 0x2000;
// X side folds (sign - 0x3F80), W side keeps sign|mag.
__device__ __forceinline__ uint32_t pack_x(uint32_t w0, uint32_t w1) {
    uint32_t u = (w0 >> 16) | (w1 & 0xFFFF0000u);
    const v2u vfloor = {0x2000, 0x2000};
    v2u m = __builtin_bit_cast(v2u, u & 0x7FFF7FFFu);
    m = __builtin_elementwise_max(m, vfloor);
    uint32_t c = (u & 0x80008000u) ^ 0xC080C080u;    // sign - 0x3F80
    v2u xp = m + __builtin_bit_cast(v2u, c);
    return __builtin_bit_cast(uint32_t, xp);
}
__device__ __forceinline__ uint32_t pack_w(uint32_t w0, uint32_t w1) {
    uint32_t v = (w0 >> 16) | (w1 & 0xFFFF0000u);
    const v2u vfloor = {0x2000, 0x2000};
    v2u m = __builtin_bit_cast(v2u, v & 0x7FFF7FFFu);
    m = __builtin_elementwise_max(m, vfloor);
    return __builtin_bit_cast(uint32_t, m) | (v & 0x80008000u);
}

__device__ __forceinline__ void lgkm0() {
    asm volatile("s_waitcnt lgkmcnt(0)" ::: "memory");
}

// ROUND 21. r20 (1-wave, no barriers): 1150 us regression — staging write
// bank conflicts (1.7e7) + scratch (WRITE 1.2GB). Reverted to r16 (558 us,
// session best, 47% matrix duty vs the 265-us MFMA floor). r17/r18/r19
// probes all neutral => classic 2-phase structural ceiling (m233). This
// round: the PROVEN escape — m201's phase template (T3+T4, +28-41%; enables
// T5). Per BK=32 chunk, 4 phases (t=0..3): {ds_reads for phase (+8 X reads
// in p0) | one staging piece (p0: X pack+write, p1: W pack+write, p2: gx
// loads, p3: gw loads)} -> s_barrier -> lgkmcnt(0) -> setprio(1) -> 16 MFMA
// (bg x a at t=p) -> setprio(0) -> s_barrier. Raw barriers never drain
// vmcnt: global prefetch stays in flight ~6 phases. Every phase's
// post-barrier lgkm0 drains own ds_writes >=3 barriers before any reader.
// Accumulation order over t unchanged -> numerics bit-identical to r16.
__global__ __launch_bounds__(256, 2)
void fpma_gemm(const uint32_t* __restrict__ X,   // [M,K] f32 bits (bf16-exact)
               const uint32_t* __restrict__ Wt,  // [N,K] f32 bits (bf16-exact)
               const float*    __restrict__ Bias,// [N]   f32 (bf16-exact)
               float* __restrict__ Out,          // [M,N] f32 (bf16-valued)
               int M, int N, int K)
{
    __shared__ uint32_t Xp[2][64 * 16];  // [buf][row*16 packed], oct-swizzled
    __shared__ uint32_t Wp[2][64 * 16];

    const int tid  = threadIdx.x;
    const int lane = tid & 63;
    const int warp = tid >> 6;
    const int wm = warp >> 1, wn = warp & 1;
    const int m0 = blockIdx.y * TM;
    const int n0 = blockIdx.x * TN;

    // compute-side roles (r15/r16-validated A/D mapping)
    const int cc = lane & 15;
    const int q  = lane >> 4;            // k-octet
    const int mi = cc >> 2;
    const int ni = cc & 3;

    const int xrd = (32 * wm + mi) * 16 + ((q ^ mi) << 2);
    int wrd[4];
    #pragma unroll
    for (int t = 0; t < 4; ++t)
        wrd[t] = (32 * wn + ni) * 16 + ((q ^ ni) << 2) + (((q + t) & 3) << 6);

    // B selectors: ones iff D col-group (cc>>2) == (q+t)&3
    u16x8 bt[4];
    #pragma unroll
    for (int t = 0; t < 4; ++t) {
        unsigned short v = ((cc >> 2) == ((q + t) & 3)) ? (unsigned short)0x3F80
                                                        : (unsigned short)0;
        bt[t] = (u16x8){v, v, v, v, v, v, v, v};
    }

    // staging roles (r16-validated, conflict-free): 64 rows x 32 k,
    // 8 raw words/thread for X and W each.
    const int srow = tid >> 2;           // 0..63
    const int soct = tid & 3;            // 0..3 (k-octet, contiguous 8 words)
    const uint32_t* xptr = X  + (size_t)(m0 + srow) * K + soct * 8;
    const uint32_t* wptr = Wt + (size_t)(n0 + srow) * K + soct * 8;
    const int st = srow * 16 + ((soct ^ (srow & 3)) << 2);

    f32x4 acc[8][2];
    #pragma unroll
    for (int a = 0; a < 8; ++a)
        #pragma unroll
        for (int bg = 0; bg < 2; ++bg) acc[a][bg] = (f32x4){0.f, 0.f, 0.f, 0.f};

    // prologue: stage chunk 0 directly; prefetch chunk 1 into regs
    {
        uint4 a0 = *(const uint4*)(xptr), a1 = *(const uint4*)(xptr + 4);
        uint4 b0 = *(const uint4*)(wptr), b1 = *(const uint4*)(wptr + 4);
        *(uint4*)&Xp[0][st] = (uint4){pack_x(a0.x,a0.y), pack_x(a0.z,a0.w),
                                      pack_x(a1.x,a1.y), pack_x(a1.z,a1.w)};
        *(uint4*)&Wp[0][st] = (uint4){pack_w(b0.x,b0.y), pack_w(b0.z,b0.w),
                                      pack_w(b1.x,b1.y), pack_w(b1.z,b1.w)};
    }
    uint4 gx0 = {0,0,0,0}, gx1 = {0,0,0,0}, gw0 = {0,0,0,0}, gw1 = {0,0,0,0};
    const int ksteps = K / BK;
    if (ksteps > 1) {
        xptr += BK; wptr += BK;
        gx0 = *(const uint4*)(xptr); gx1 = *(const uint4*)(xptr + 4);
        gw0 = *(const uint4*)(wptr); gw1 = *(const uint4*)(wptr + 4);
    }
    __syncthreads();   // one-time full drain; publishes chunk-0 staging

#define PHASE_MFMA(T, WA, WB)                                             \
    __builtin_amdgcn_s_setprio(1);                                        \
    _Pragma("unroll")                                                     \
    for (int a = 0; a < 8; ++a) {                                         \
        u16x8 p = xf[a] + (WA);                                           \
        acc[a][0] = __builtin_amdgcn_mfma_f32_16x16x32_bf16(              \
            __builtin_bit_cast(s16x8, p),                                 \
            __builtin_bit_cast(s16x8, bt[T]), acc[a][0], 0, 0, 0);        \
    }                                                                     \
    _Pragma("unroll")                                                     \
    for (int a = 0; a < 8; ++a) {                                         \
        u16x8 p = xf[a] + (WB);                                           \
        acc[a][1] = __builtin_amdgcn_mfma_f32_16x16x32_bf16(              \
            __builtin_bit_cast(s16x8, p),                                 \
            __builtin_bit_cast(s16x8, bt[T]), acc[a][1], 0, 0, 0);        \
    }                                                                     \
    __builtin_amdgcn_s_setprio(0);

    #pragma unroll 1
    for (int kt = 0; kt < ksteps; ++kt) {
        const int cur = kt & 1;
        const bool stage = (kt + 1 < ksteps);
        const bool pre   = (kt + 2 < ksteps);
        u16x8 xf[8];

        // ---------- phase 0: X reads + W(t=0) reads | stage X ----------
        #pragma unroll
        for (int a = 0; a < 8; ++a)
            xf[a] = __builtin_bit_cast(u16x8,
                        *(const uint4*)&Xp[cur][xrd + a * 64]);
        u16x8 w0a = __builtin_bit_cast(u16x8, *(const uint4*)&Wp[cur][wrd[0]]);
        u16x8 w0b = __builtin_bit_cast(u16x8, *(const uint4*)&Wp[cur][wrd[0] + 256]);
        if (stage)
            *(uint4*)&Xp[cur ^ 1][st] = (uint4){pack_x(gx0.x,gx0.y), pack_x(gx0.z,gx0.w),
                                                pack_x(gx1.x,gx1.y), pack_x(gx1.z,gx1.w)};
        __builtin_amdgcn_s_barrier();
        lgkm0();
        PHASE_MFMA(0, w0a, w0b)
        __builtin_amdgcn_s_barrier();

        // ---------- phase 1: W(t=1) reads | stage W ----------
        u16x8 w1a = __builtin_bit_cast(u16x8, *(const uint4*)&Wp[cur][wrd[1]]);
        u16x8 w1b = __builtin_bit_cast(u16x8, *(const uint4*)&Wp[cur][wrd[1] + 256]);
        if (stage)
            *(uint4*)&Wp[cur ^ 1][st] = (uint4){pack_w(gw0.x,gw0.y), pack_w(gw0.z,gw0.w),
                                                pack_w(gw1.x,gw1.y), pack_w(gw1.z,gw1.w)};
        __builtin_amdgcn_s_barrier();
        lgkm0();
        PHASE_MFMA(1, w1a, w1b)
        __builtin_amdgcn_s_barrier();

        // ---------- phase 2: W(t=2) reads | prefetch next X ----------
        u16x8 w2a = __builtin_bit_cast(u16x8, *(const uint4*)&Wp[cur][wrd[2]]);
        u16x8 w2b = __builtin_bit_cast(u16x8, *(const uint4*)&Wp[cur][wrd[2] + 256]);
        if (pre) {
            xptr += BK;
            gx0 = *(const uint4*)(xptr); gx1 = *(const uint4*)(xptr + 4);
        }
        __builtin_amdgcn_s_barrier();
        lgkm0();
        PHASE_MFMA(2, w2a, w2b)
        __builtin_amdgcn_s_barrier();

        // ---------- phase 3: W(t=3) reads | prefetch next W ----------
        u16x8 w3a = __builtin_bit_cast(u16x8, *(const uint4*)&Wp[cur][wrd[3]]);
        u16x8 w3b = __builtin_bit_cast(u16x8, *(const uint4*)&Wp[cur][wrd[3] + 256]);
        if (pre) {
            wptr += BK;
            gw0 = *(const uint4*)(wptr); gw1 = *(const uint4*)(wptr + 4);
        }
        __builtin_amdgcn_s_barrier();
        lgkm0();
        PHASE_MFMA(3, w3a, w3b)
        __builtin_amdgcn_s_barrier();
    }
#undef PHASE_MFMA

    // Epilogue (r16-validated). acc[a][bg]: lane (cc,q), elem j =
    // out(m0+32wm+4a+q, n0+32wn+16bg+4*(cc>>2)+j); lane stores a's with
    // a&3 == cc&3 (disjoint, complete cover of 64x64 tile).
    const int g = cc >> 2;
    f32x4 bias_[2];
    #pragma unroll
    for (int bg = 0; bg < 2; ++bg)
        bias_[bg] = *(const f32x4*)&Bias[n0 + 32 * wn + 16 * bg + 4 * g];

    #pragma unroll
    for (int a = 0; a < 8; ++a) {
        if ((cc & 3) == (a & 3)) {
            #pragma unroll
            for (int bg = 0; bg < 2; ++bg) {
                float o[4];
                #pragma unroll
                for (int j = 0; j < 4; ++j)
                    o[j] = bf16_to_f32(rnd_bf16(
                               bf16_to_f32(rnd_bf16(acc[a][bg][j])) + bias_[bg][j]));
                const size_t row = (size_t)(m0 + 32 * wm + 4 * a + q) * N;
                *(float4*)&Out[row + n0 + 32 * wn + 16 * bg + 4 * g] =
                    make_float4(o[0], o[1], o[2], o[3]);
            }
        }
    }
}

extern "C" void kernel_launch(void* const* d_in, const int* in_sizes, int n_in,
                              void* d_out, int out_size, void* d_ws, size_t ws_size,
                              hipStream_t stream) {
    (void)n_in; (void)d_ws; (void)ws_size; (void)out_size;
    const uint32_t* X = (const uint32_t*)d_in[0];   // f32 words (bf16-exact)
    const uint32_t* W = (const uint32_t*)d_in[1];
    const float*    B = (const float*)d_in[2];
    float* O = (float*)d_out;                       // f32 out (bf16-valued)

    int N = in_sizes[2];                       // bias [1,N], elements
    int K = (N > 0) ? in_sizes[1] / N : 0;     // weight [N,K]
    int M = (K > 0) ? in_sizes[0] / K : 0;     // input [M,K]
    if (N <= 0 || K <= 0 || M <= 0 ||
        (long long)N * K != (long long)in_sizes[1] ||
        (long long)M * K != (long long)in_sizes[0] ||
        (M % TM) || (N % TN) || (K % BK)) {
        M = 4096; K = 2048; N = 2048;          // documented problem shape
    }

    dim3 grid(N / TN, M / TM);
    fpma_gemm<<<grid, 256, 0, stream>>>(X, W, B, O, M, N, K);
}

// Round 10
// 526.892 us; speedup vs baseline: 2.1831x; 1.1131x over previous
//
#include <hip/hip_runtime.h>
#include <stdint.h>

typedef unsigned short v2u   __attribute__((ext_vector_type(2)));
typedef unsigned short u16x8 __attribute__((ext_vector_type(8)));
typedef short          s16x8 __attribute__((ext_vector_type(8)));
typedef float          f32x4 __attribute__((ext_vector_type(4)));

#define TM 64
#define TN 64
#define BK 32

__device__ __forceinline__ uint32_t rnd_bf16(float f) {
    uint32_t u = __builtin_bit_cast(uint32_t, f);
    return (u + 0x7FFFu + ((u >> 16) & 1u)) >> 16;   // RNE f32 -> bf16 (finite)
}
__device__ __forceinline__ float bf16_to_f32(uint32_t bits16) {
    return __builtin_bit_cast(float, bits16 << 16);
}

// HW-validated pack transforms (r12/r15): mag floored at 0x2000;
// X side folds (sign - 0x3F80), W side keeps sign|mag.
__device__ __forceinline__ uint32_t pack_x(uint32_t w0, uint32_t w1) {
    uint32_t u = (w0 >> 16) | (w1 & 0xFFFF0000u);
    const v2u vfloor = {0x2000, 0x2000};
    v2u m = __builtin_bit_cast(v2u, u & 0x7FFF7FFFu);
    m = __builtin_elementwise_max(m, vfloor);
    uint32_t c = (u & 0x80008000u) ^ 0xC080C080u;    // sign - 0x3F80
    v2u xp = m + __builtin_bit_cast(v2u, c);
    return __builtin_bit_cast(uint32_t, xp);
}
__device__ __forceinline__ uint32_t pack_w(uint32_t w0, uint32_t w1) {
    uint32_t v = (w0 >> 16) | (w1 & 0xFFFF0000u);
    const v2u vfloor = {0x2000, 0x2000};
    v2u m = __builtin_bit_cast(v2u, v & 0x7FFF7FFFu);
    m = __builtin_elementwise_max(m, vfloor);
    return __builtin_bit_cast(uint32_t, m) | (v & 0x80008000u);
}

// Pre-pack pass: 4 raw f32-bit words -> 2 packed u32 (grid-stride, BW-bound).
__global__ void pack_kernel(const uint32_t* __restrict__ in,
                            uint32_t* __restrict__ out, int n4, int mode)
{
    int i = blockIdx.x * blockDim.x + threadIdx.x;
    const int stride = gridDim.x * blockDim.x;
    for (; i < n4; i += stride) {
        uint4 v = ((const uint4*)in)[i];
        uint2 o;
        if (mode == 0) { o.x = pack_x(v.x, v.y); o.y = pack_x(v.z, v.w); }
        else           { o.x = pack_w(v.x, v.y); o.y = pack_w(v.z, v.w); }
        ((uint2*)out)[i] = o;
    }
}

// ROUND 22. r16-r21 invariant at 558-586 us across ALL sync-structure probes
// -> feed-rate model: each MFMA needs 4 v_pk_add_u16 (8 VALU-cyc) + ~3 cyc
// amortized in-loop pack staging vs 4.85-cyc MFMA service => MfmaUtil cap
// 4.85/11 = 44% = measured (41-47%, wave-count-invariant since VALU is
// per-SIMD shared). Lever: remove the redundant pack (each X element packed
// 32x, W 64x). PRE path: inputs pre-packed into d_ws by pack_kernel; GEMM
// stages via global_load_lds width-16 (m97): LDS dest LINEAR tid*16B,
// swizzle moved to per-lane GLOBAL source octet (rule #21/m173) -> read
// formulas unchanged from validated r16. No staging VALU, no prefetch regs.
// Feed -> ~8.4 cyc/MFMA; 3 waves/SIMD oversubscribe matrix pipe.
// Fallback (!PRE, ws too small): exact r16 in-kernel-pack path.
template<bool PRE>
__global__ __launch_bounds__(256, 3)
void fpma_gemm(const uint32_t* __restrict__ X,   // PRE: packed [M,K/2] | raw [M,K]
               const uint32_t* __restrict__ Wt,  // PRE: packed [N,K/2] | raw [N,K]
               const float*    __restrict__ Bias,// [N] f32 (bf16-exact)
               float* __restrict__ Out,          // [M,N] f32 (bf16-valued)
               int M, int N, int K)
{
    __shared__ uint32_t Xp[2][64 * 16];  // [buf][row*16 packed], oct-swizzled
    __shared__ uint32_t Wp[2][64 * 16];

    const int tid  = threadIdx.x;
    const int lane = tid & 63;
    const int warp = tid >> 6;
    const int wm = warp >> 1, wn = warp & 1;
    const int m0 = blockIdx.y * TM;
    const int n0 = blockIdx.x * TN;

    // compute-side roles (r15/r16-validated A/D mapping)
    const int cc = lane & 15;
    const int q  = lane >> 4;            // k-octet
    const int mi = cc >> 2;
    const int ni = cc & 3;

    const int xrd = (32 * wm + mi) * 16 + ((q ^ mi) << 2);
    int wrd[4];
    #pragma unroll
    for (int t = 0; t < 4; ++t)
        wrd[t] = (32 * wn + ni) * 16 + ((q ^ ni) << 2) + (((q + t) & 3) << 6);

    // B selectors: ones iff D col-group (cc>>2) == (q+t)&3
    u16x8 bt[4];
    #pragma unroll
    for (int t = 0; t < 4; ++t) {
        unsigned short v = ((cc >> 2) == ((q + t) & 3)) ? (unsigned short)0x3F80
                                                        : (unsigned short)0;
        bt[t] = (u16x8){v, v, v, v, v, v, v, v};
    }

    // staging roles
    const int srow = tid >> 2;           // 0..63
    const int soct = tid & 3;            // 0..3
    const int ksteps = K / BK;

    f32x4 acc[8][2];
    #pragma unroll
    for (int a = 0; a < 8; ++a)
        #pragma unroll
        for (int bg = 0; bg < 2; ++bg) acc[a][bg] = (f32x4){0.f, 0.f, 0.f, 0.f};

    // --- PRE path state: packed-source pointers (swizzled octet) ---
    const int Kp = K >> 1;               // packed words per row
    const uint32_t* xsrc = X  + (size_t)(m0 + srow) * Kp + ((soct ^ (srow & 3)) << 2);
    const uint32_t* wsrc = Wt + (size_t)(n0 + srow) * Kp + ((soct ^ (srow & 3)) << 2);
    // --- fallback path state: raw-source pointers + prefetch regs ---
    const uint32_t* xptr = X  + (size_t)(m0 + srow) * K + soct * 8;
    const uint32_t* wptr = Wt + (size_t)(n0 + srow) * K + soct * 8;
    const int st = srow * 16 + ((soct ^ (srow & 3)) << 2);
    uint4 gx0 = {0,0,0,0}, gx1 = {0,0,0,0}, gw0 = {0,0,0,0}, gw1 = {0,0,0,0};

    if constexpr (PRE) {
        // prologue: DMA chunk 0 into buf 0 (LDS dest linear: tid*16B)
        __builtin_amdgcn_global_load_lds(xsrc, &Xp[0][tid << 2], 16, 0, 0);
        __builtin_amdgcn_global_load_lds(wsrc, &Wp[0][tid << 2], 16, 0, 0);
        xsrc += 16; wsrc += 16;
    } else {
        uint4 a0 = *(const uint4*)(xptr), a1 = *(const uint4*)(xptr + 4);
        uint4 b0 = *(const uint4*)(wptr), b1 = *(const uint4*)(wptr + 4);
        *(uint4*)&Xp[0][st] = (uint4){pack_x(a0.x,a0.y), pack_x(a0.z,a0.w),
                                      pack_x(a1.x,a1.y), pack_x(a1.z,a1.w)};
        *(uint4*)&Wp[0][st] = (uint4){pack_w(b0.x,b0.y), pack_w(b0.z,b0.w),
                                      pack_w(b1.x,b1.y), pack_w(b1.z,b1.w)};
        if (ksteps > 1) {
            xptr += BK; wptr += BK;
            gx0 = *(const uint4*)(xptr); gx1 = *(const uint4*)(xptr + 4);
            gw0 = *(const uint4*)(wptr); gw1 = *(const uint4*)(wptr + 4);
        }
    }
    __syncthreads();   // full drain: chunk-0 staging visible

    #pragma unroll 1
    for (int kt = 0; kt < ksteps; ++kt) {
        const int cur = kt & 1;
        if (kt + 1 < ksteps) {
            if constexpr (PRE) {
                __builtin_amdgcn_global_load_lds(xsrc, &Xp[cur ^ 1][tid << 2], 16, 0, 0);
                __builtin_amdgcn_global_load_lds(wsrc, &Wp[cur ^ 1][tid << 2], 16, 0, 0);
                xsrc += 16; wsrc += 16;
            } else {
                *(uint4*)&Xp[cur ^ 1][st] = (uint4){pack_x(gx0.x,gx0.y), pack_x(gx0.z,gx0.w),
                                                    pack_x(gx1.x,gx1.y), pack_x(gx1.z,gx1.w)};
                *(uint4*)&Wp[cur ^ 1][st] = (uint4){pack_w(gw0.x,gw0.y), pack_w(gw0.z,gw0.w),
                                                    pack_w(gw1.x,gw1.y), pack_w(gw1.z,gw1.w)};
                if (kt + 2 < ksteps) {
                    xptr += BK; wptr += BK;
                    gx0 = *(const uint4*)(xptr); gx1 = *(const uint4*)(xptr + 4);
                    gw0 = *(const uint4*)(wptr); gw1 = *(const uint4*)(wptr + 4);
                }
            }
        }

        u16x8 xf[8];
        #pragma unroll
        for (int a = 0; a < 8; ++a)
            xf[a] = __builtin_bit_cast(u16x8,
                        *(const uint4*)&Xp[cur][xrd + a * 64]);

        __builtin_amdgcn_s_setprio(1);
        #pragma unroll
        for (int bg = 0; bg < 2; ++bg) {
            u16x8 wf[4];
            #pragma unroll
            for (int t = 0; t < 4; ++t)
                wf[t] = __builtin_bit_cast(u16x8,
                            *(const uint4*)&Wp[cur][wrd[t] + bg * 256]);
            #pragma unroll
            for (int t = 0; t < 4; ++t)
                #pragma unroll
                for (int a = 0; a < 8; ++a) {
                    u16x8 p = xf[a] + wf[t];           // 4x v_pk_add_u16
                    acc[a][bg] = __builtin_amdgcn_mfma_f32_16x16x32_bf16(
                        __builtin_bit_cast(s16x8, p),
                        __builtin_bit_cast(s16x8, bt[t]),
                        acc[a][bg], 0, 0, 0);
                }
        }
        __builtin_amdgcn_s_setprio(0);
        __syncthreads();   // drains vmcnt (DMA into cur^1) + lgkm; publishes
    }

    // Epilogue (r16-validated). acc[a][bg]: lane (cc,q), elem j =
    // out(m0+32wm+4a+q, n0+32wn+16bg+4*(cc>>2)+j); lane stores a's with
    // a&3 == cc&3 (disjoint, complete cover of 64x64 tile).
    const int g = cc >> 2;
    f32x4 bias_[2];
    #pragma unroll
    for (int bg = 0; bg < 2; ++bg)
        bias_[bg] = *(const f32x4*)&Bias[n0 + 32 * wn + 16 * bg + 4 * g];

    #pragma unroll
    for (int a = 0; a < 8; ++a) {
        if ((cc & 3) == (a & 3)) {
            #pragma unroll
            for (int bg = 0; bg < 2; ++bg) {
                float o[4];
                #pragma unroll
                for (int j = 0; j < 4; ++j)
                    o[j] = bf16_to_f32(rnd_bf16(
                               bf16_to_f32(rnd_bf16(acc[a][bg][j])) + bias_[bg][j]));
                const size_t row = (size_t)(m0 + 32 * wm + 4 * a + q) * N;
                *(float4*)&Out[row + n0 + 32 * wn + 16 * bg + 4 * g] =
                    make_float4(o[0], o[1], o[2], o[3]);
            }
        }
    }
}

extern "C" void kernel_launch(void* const* d_in, const int* in_sizes, int n_in,
                              void* d_out, int out_size, void* d_ws, size_t ws_size,
                              hipStream_t stream) {
    (void)n_in; (void)out_size;
    const uint32_t* X = (const uint32_t*)d_in[0];   // f32 words (bf16-exact)
    const uint32_t* W = (const uint32_t*)d_in[1];
    const float*    B = (const float*)d_in[2];
    float* O = (float*)d_out;                       // f32 out (bf16-valued)

    int N = in_sizes[2];                       // bias [1,N], elements
    int K = (N > 0) ? in_sizes[1] / N : 0;     // weight [N,K]
    int M = (K > 0) ? in_sizes[0] / K : 0;     // input [M,K]
    if (N <= 0 || K <= 0 || M <= 0 ||
        (long long)N * K != (long long)in_sizes[1] ||
        (long long)M * K != (long long)in_sizes[0] ||
        (M % TM) || (N % TN) || (K % BK) || (K % 8)) {
        M = 4096; K = 2048; N = 2048;          // documented problem shape
    }

    const size_t xq_words = (size_t)M * (K / 2);
    const size_t wq_words = (size_t)N * (K / 2);
    const size_t need = (xq_words + wq_words) * 4;

    dim3 grid(N / TN, M / TM);
    if (d_ws != nullptr && ws_size >= need) {
        uint32_t* Xq = (uint32_t*)d_ws;
        uint32_t* Wq = Xq + xq_words;
        pack_kernel<<<1024, 256, 0, stream>>>(X, Xq, (int)(xq_words / 2), 0);
        pack_kernel<<<1024, 256, 0, stream>>>(W, Wq, (int)(wq_words / 2), 1);
        fpma_gemm<true><<<grid, 256, 0, stream>>>(Xq, Wq, B, O, M, N, K);
    } else {
        fpma_gemm<false><<<grid, 256, 0, stream>>>(X, W, B, O, M, N, K);
    }
}

// Round 11
// 506.531 us; speedup vs baseline: 2.2708x; 1.0402x over previous
//
#include <hip/hip_runtime.h>
#include <stdint.h>

typedef unsigned short v2u   __attribute__((ext_vector_type(2)));
typedef unsigned short u16x8 __attribute__((ext_vector_type(8)));
typedef short          s16x8 __attribute__((ext_vector_type(8)));
typedef float          f32x4 __attribute__((ext_vector_type(4)));

#define TM 64
#define TN 64

__device__ __forceinline__ uint32_t rnd_bf16(float f) {
    uint32_t u = __builtin_bit_cast(uint32_t, f);
    return (u + 0x7FFFu + ((u >> 16) & 1u)) >> 16;   // RNE f32 -> bf16 (finite)
}
__device__ __forceinline__ float bf16_to_f32(uint32_t bits16) {
    return __builtin_bit_cast(float, bits16 << 16);
}

// HW-validated pack transforms (r12/r15): mag floored at 0x2000;
// X side folds (sign - 0x3F80), W side keeps sign|mag.
__device__ __forceinline__ uint32_t pack_x(uint32_t w0, uint32_t w1) {
    uint32_t u = (w0 >> 16) | (w1 & 0xFFFF0000u);
    const v2u vfloor = {0x2000, 0x2000};
    v2u m = __builtin_bit_cast(v2u, u & 0x7FFF7FFFu);
    m = __builtin_elementwise_max(m, vfloor);
    uint32_t c = (u & 0x80008000u) ^ 0xC080C080u;    // sign - 0x3F80
    v2u xp = m + __builtin_bit_cast(v2u, c);
    return __builtin_bit_cast(uint32_t, xp);
}
__device__ __forceinline__ uint32_t pack_w(uint32_t w0, uint32_t w1) {
    uint32_t v = (w0 >> 16) | (w1 & 0xFFFF0000u);
    const v2u vfloor = {0x2000, 0x2000};
    v2u m = __builtin_bit_cast(v2u, v & 0x7FFF7FFFu);
    m = __builtin_elementwise_max(m, vfloor);
    return __builtin_bit_cast(uint32_t, m) | (v & 0x80008000u);
}

// Pre-pack pass: 4 raw f32-bit words -> 2 packed u32 (grid-stride, BW-bound).
__global__ void pack_kernel(const uint32_t* __restrict__ in,
                            uint32_t* __restrict__ out, int n4, int mode)
{
    int i = blockIdx.x * blockDim.x + threadIdx.x;
    const int stride = gridDim.x * blockDim.x;
    for (; i < n4; i += stride) {
        uint4 v = ((const uint4*)in)[i];
        uint2 o;
        if (mode == 0) { o.x = pack_x(v.x, v.y); o.y = pack_x(v.z, v.w); }
        else           { o.x = pack_w(v.x, v.y); o.y = pack_w(v.z, v.w); }
        ((uint2*)out)[i] = o;
    }
}

// ROUND 23. r22: 527 us total (GEMM dispatch 486), MfmaUtil 51.8% — matrix
// busy 252 us = the 265-us MFMA floor; pre-pack removed the VALU feed tax.
// Per-CU per chunk-round budgets: matrix 3726 cyc > LDS 2304 > VALU ~1700,
// yet wall/round ~6860 cyc => ~3100 cyc/round of barrier bubble (skew +
// drain + refill), paid 64x. r18's BK=64 failed from PREFETCH-REG spill;
// DMA staging has no prefetch regs, so BK=64 is now safe: each chunk = two
// validated 32-k sub-tiles staged by 4 global_load_lds, one barrier per 64k.
// Rounds 64->32. Accumulation order identical (k-ascending) -> bit-exact.
__global__ __launch_bounds__(256, 3)
void fpma_gemm_pre(const uint32_t* __restrict__ Xq,  // packed [M,K/2]
                   const uint32_t* __restrict__ Wq,  // packed [N,K/2]
                   const float*    __restrict__ Bias,// [N] f32 (bf16-exact)
                   float* __restrict__ Out,          // [M,N] f32 (bf16-valued)
                   int M, int N, int K)
{
    __shared__ uint32_t Xp[2][2][64 * 16];  // [buf][ksub][row*16], oct-swizzled
    __shared__ uint32_t Wp[2][2][64 * 16];

    const int tid  = threadIdx.x;
    const int lane = tid & 63;
    const int warp = tid >> 6;
    const int wm = warp >> 1, wn = warp & 1;
    const int m0 = blockIdx.y * TM;
    const int n0 = blockIdx.x * TN;

    // compute-side roles (r15/r16-validated A/D mapping)
    const int cc = lane & 15;
    const int q  = lane >> 4;            // k-octet within a 32-k sub-tile
    const int mi = cc >> 2;
    const int ni = cc & 3;

    const int xrd = (32 * wm + mi) * 16 + ((q ^ mi) << 2);
    int wrd[4];
    #pragma unroll
    for (int t = 0; t < 4; ++t)
        wrd[t] = (32 * wn + ni) * 16 + ((q ^ ni) << 2) + (((q + t) & 3) << 6);

    // B selectors: ones iff D col-group (cc>>2) == (q+t)&3
    u16x8 bt[4];
    #pragma unroll
    for (int t = 0; t < 4; ++t) {
        unsigned short v = ((cc >> 2) == ((q + t) & 3)) ? (unsigned short)0x3F80
                                                        : (unsigned short)0;
        bt[t] = (u16x8){v, v, v, v, v, v, v, v};
    }

    // staging roles: DMA dest linear tid*16B per sub-tile; swizzle moved to
    // the per-lane GLOBAL source octet (rule #21/m173; r22-validated).
    const int srow = tid >> 2;           // 0..63
    const int soct = tid & 3;            // 0..3
    const int Kp = K >> 1;               // packed words per row
    const int swz = (soct ^ (srow & 3)) << 2;
    const uint32_t* xsrc = Xq + (size_t)(m0 + srow) * Kp + swz;
    const uint32_t* wsrc = Wq + (size_t)(n0 + srow) * Kp + swz;

    f32x4 acc[8][2];
    #pragma unroll
    for (int a = 0; a < 8; ++a)
        #pragma unroll
        for (int bg = 0; bg < 2; ++bg) acc[a][bg] = (f32x4){0.f, 0.f, 0.f, 0.f};

    // prologue: DMA chunk 0 (both 32-k sub-tiles) into buf 0
    __builtin_amdgcn_global_load_lds(xsrc,      &Xp[0][0][tid << 2], 16, 0, 0);
    __builtin_amdgcn_global_load_lds(xsrc + 16, &Xp[0][1][tid << 2], 16, 0, 0);
    __builtin_amdgcn_global_load_lds(wsrc,      &Wp[0][0][tid << 2], 16, 0, 0);
    __builtin_amdgcn_global_load_lds(wsrc + 16, &Wp[0][1][tid << 2], 16, 0, 0);
    xsrc += 32; wsrc += 32;
    __syncthreads();   // drain: chunk-0 staging visible

    const int ksteps = K / 64;
    #pragma unroll 1
    for (int kt = 0; kt < ksteps; ++kt) {
        const int cur = kt & 1;
        if (kt + 1 < ksteps) {
            __builtin_amdgcn_global_load_lds(xsrc,      &Xp[cur ^ 1][0][tid << 2], 16, 0, 0);
            __builtin_amdgcn_global_load_lds(xsrc + 16, &Xp[cur ^ 1][1][tid << 2], 16, 0, 0);
            __builtin_amdgcn_global_load_lds(wsrc,      &Wp[cur ^ 1][0][tid << 2], 16, 0, 0);
            __builtin_amdgcn_global_load_lds(wsrc + 16, &Wp[cur ^ 1][1][tid << 2], 16, 0, 0);
            xsrc += 32; wsrc += 32;
        }

        __builtin_amdgcn_s_setprio(1);
        #pragma unroll
        for (int ks = 0; ks < 2; ++ks) {
            u16x8 xf[8];
            #pragma unroll
            for (int a = 0; a < 8; ++a)
                xf[a] = __builtin_bit_cast(u16x8,
                            *(const uint4*)&Xp[cur][ks][xrd + a * 64]);
            #pragma unroll
            for (int bg = 0; bg < 2; ++bg) {
                u16x8 wf[4];
                #pragma unroll
                for (int t = 0; t < 4; ++t)
                    wf[t] = __builtin_bit_cast(u16x8,
                                *(const uint4*)&Wp[cur][ks][wrd[t] + bg * 256]);
                #pragma unroll
                for (int t = 0; t < 4; ++t)
                    #pragma unroll
                    for (int a = 0; a < 8; ++a) {
                        u16x8 p = xf[a] + wf[t];       // 4x v_pk_add_u16
                        acc[a][bg] = __builtin_amdgcn_mfma_f32_16x16x32_bf16(
                            __builtin_bit_cast(s16x8, p),
                            __builtin_bit_cast(s16x8, bt[t]),
                            acc[a][bg], 0, 0, 0);
                    }
            }
        }
        __builtin_amdgcn_s_setprio(0);
        __syncthreads();   // drains DMA into cur^1 + lgkm; publishes
    }

    // Epilogue (r16-validated). acc[a][bg]: lane (cc,q), elem j =
    // out(m0+32wm+4a+q, n0+32wn+16bg+4*(cc>>2)+j); lane stores a's with
    // a&3 == cc&3 (disjoint, complete cover of 64x64 tile).
    const int g = cc >> 2;
    f32x4 bias_[2];
    #pragma unroll
    for (int bg = 0; bg < 2; ++bg)
        bias_[bg] = *(const f32x4*)&Bias[n0 + 32 * wn + 16 * bg + 4 * g];

    #pragma unroll
    for (int a = 0; a < 8; ++a) {
        if ((cc & 3) == (a & 3)) {
            #pragma unroll
            for (int bg = 0; bg < 2; ++bg) {
                float o[4];
                #pragma unroll
                for (int j = 0; j < 4; ++j)
                    o[j] = bf16_to_f32(rnd_bf16(
                               bf16_to_f32(rnd_bf16(acc[a][bg][j])) + bias_[bg][j]));
                const size_t row = (size_t)(m0 + 32 * wm + 4 * a + q) * N;
                *(float4*)&Out[row + n0 + 32 * wn + 16 * bg + 4 * g] =
                    make_float4(o[0], o[1], o[2], o[3]);
            }
        }
    }
}

// Fallback (ws too small): r16 path — in-kernel pack, BK=32, reg prefetch.
__global__ __launch_bounds__(256, 3)
void fpma_gemm_fb(const uint32_t* __restrict__ X, const uint32_t* __restrict__ Wt,
                  const float* __restrict__ Bias, float* __restrict__ Out,
                  int M, int N, int K)
{
    __shared__ uint32_t Xp[2][64 * 16];
    __shared__ uint32_t Wp[2][64 * 16];

    const int tid  = threadIdx.x;
    const int lane = tid & 63;
    const int warp = tid >> 6;
    const int wm = warp >> 1, wn = warp & 1;
    const int m0 = blockIdx.y * TM;
    const int n0 = blockIdx.x * TN;
    const int cc = lane & 15;
    const int q  = lane >> 4;
    const int mi = cc >> 2;
    const int ni = cc & 3;
    const int xrd = (32 * wm + mi) * 16 + ((q ^ mi) << 2);
    int wrd[4];
    #pragma unroll
    for (int t = 0; t < 4; ++t)
        wrd[t] = (32 * wn + ni) * 16 + ((q ^ ni) << 2) + (((q + t) & 3) << 6);
    u16x8 bt[4];
    #pragma unroll
    for (int t = 0; t < 4; ++t) {
        unsigned short v = ((cc >> 2) == ((q + t) & 3)) ? (unsigned short)0x3F80
                                                        : (unsigned short)0;
        bt[t] = (u16x8){v, v, v, v, v, v, v, v};
    }
    const int srow = tid >> 2;
    const int soct = tid & 3;
    const uint32_t* xptr = X  + (size_t)(m0 + srow) * K + soct * 8;
    const uint32_t* wptr = Wt + (size_t)(n0 + srow) * K + soct * 8;
    const int st = srow * 16 + ((soct ^ (srow & 3)) << 2);

    f32x4 acc[8][2];
    #pragma unroll
    for (int a = 0; a < 8; ++a)
        #pragma unroll
        for (int bg = 0; bg < 2; ++bg) acc[a][bg] = (f32x4){0.f, 0.f, 0.f, 0.f};

    {
        uint4 a0 = *(const uint4*)(xptr), a1 = *(const uint4*)(xptr + 4);
        uint4 b0 = *(const uint4*)(wptr), b1 = *(const uint4*)(wptr + 4);
        *(uint4*)&Xp[0][st] = (uint4){pack_x(a0.x,a0.y), pack_x(a0.z,a0.w),
                                      pack_x(a1.x,a1.y), pack_x(a1.z,a1.w)};
        *(uint4*)&Wp[0][st] = (uint4){pack_w(b0.x,b0.y), pack_w(b0.z,b0.w),
                                      pack_w(b1.x,b1.y), pack_w(b1.z,b1.w)};
    }
    uint4 gx0 = {0,0,0,0}, gx1 = {0,0,0,0}, gw0 = {0,0,0,0}, gw1 = {0,0,0,0};
    const int ksteps = K / 32;
    if (ksteps > 1) {
        xptr += 32; wptr += 32;
        gx0 = *(const uint4*)(xptr); gx1 = *(const uint4*)(xptr + 4);
        gw0 = *(const uint4*)(wptr); gw1 = *(const uint4*)(wptr + 4);
    }
    __syncthreads();

    #pragma unroll 1
    for (int kt = 0; kt < ksteps; ++kt) {
        const int cur = kt & 1;
        if (kt + 1 < ksteps) {
            *(uint4*)&Xp[cur ^ 1][st] = (uint4){pack_x(gx0.x,gx0.y), pack_x(gx0.z,gx0.w),
                                                pack_x(gx1.x,gx1.y), pack_x(gx1.z,gx1.w)};
            *(uint4*)&Wp[cur ^ 1][st] = (uint4){pack_w(gw0.x,gw0.y), pack_w(gw0.z,gw0.w),
                                                pack_w(gw1.x,gw1.y), pack_w(gw1.z,gw1.w)};
            if (kt + 2 < ksteps) {
                xptr += 32; wptr += 32;
                gx0 = *(const uint4*)(xptr); gx1 = *(const uint4*)(xptr + 4);
                gw0 = *(const uint4*)(wptr); gw1 = *(const uint4*)(wptr + 4);
            }
        }
        u16x8 xf[8];
        #pragma unroll
        for (int a = 0; a < 8; ++a)
            xf[a] = __builtin_bit_cast(u16x8, *(const uint4*)&Xp[cur][xrd + a * 64]);
        #pragma unroll
        for (int bg = 0; bg < 2; ++bg) {
            u16x8 wf[4];
            #pragma unroll
            for (int t = 0; t < 4; ++t)
                wf[t] = __builtin_bit_cast(u16x8, *(const uint4*)&Wp[cur][wrd[t] + bg * 256]);
            #pragma unroll
            for (int t = 0; t < 4; ++t)
                #pragma unroll
                for (int a = 0; a < 8; ++a) {
                    u16x8 p = xf[a] + wf[t];
                    acc[a][bg] = __builtin_amdgcn_mfma_f32_16x16x32_bf16(
                        __builtin_bit_cast(s16x8, p),
                        __builtin_bit_cast(s16x8, bt[t]), acc[a][bg], 0, 0, 0);
                }
        }
        __syncthreads();
    }

    const int g = cc >> 2;
    f32x4 bias_[2];
    #pragma unroll
    for (int bg = 0; bg < 2; ++bg)
        bias_[bg] = *(const f32x4*)&Bias[n0 + 32 * wn + 16 * bg + 4 * g];
    #pragma unroll
    for (int a = 0; a < 8; ++a) {
        if ((cc & 3) == (a & 3)) {
            #pragma unroll
            for (int bg = 0; bg < 2; ++bg) {
                float o[4];
                #pragma unroll
                for (int j = 0; j < 4; ++j)
                    o[j] = bf16_to_f32(rnd_bf16(
                               bf16_to_f32(rnd_bf16(acc[a][bg][j])) + bias_[bg][j]));
                const size_t row = (size_t)(m0 + 32 * wm + 4 * a + q) * N;
                *(float4*)&Out[row + n0 + 32 * wn + 16 * bg + 4 * g] =
                    make_float4(o[0], o[1], o[2], o[3]);
            }
        }
    }
}

extern "C" void kernel_launch(void* const* d_in, const int* in_sizes, int n_in,
                              void* d_out, int out_size, void* d_ws, size_t ws_size,
                              hipStream_t stream) {
    (void)n_in; (void)out_size;
    const uint32_t* X = (const uint32_t*)d_in[0];   // f32 words (bf16-exact)
    const uint32_t* W = (const uint32_t*)d_in[1];
    const float*    B = (const float*)d_in[2];
    float* O = (float*)d_out;                       // f32 out (bf16-valued)

    int N = in_sizes[2];                       // bias [1,N], elements
    int K = (N > 0) ? in_sizes[1] / N : 0;     // weight [N,K]
    int M = (K > 0) ? in_sizes[0] / K : 0;     // input [M,K]
    if (N <= 0 || K <= 0 || M <= 0 ||
        (long long)N * K != (long long)in_sizes[1] ||
        (long long)M * K != (long long)in_sizes[0] ||
        (M % TM) || (N % TN) || (K % 64)) {
        M = 4096; K = 2048; N = 2048;          // documented problem shape
    }

    const size_t xq_words = (size_t)M * (K / 2);
    const size_t wq_words = (size_t)N * (K / 2);
    const size_t need = (xq_words + wq_words) * 4;

    dim3 grid(N / TN, M / TM);
    if (d_ws != nullptr && ws_size >= need) {
        uint32_t* Xq = (uint32_t*)d_ws;
        uint32_t* Wq = Xq + xq_words;
        pack_kernel<<<1024, 256, 0, stream>>>(X, Xq, (int)(xq_words / 2), 0);
        pack_kernel<<<1024, 256, 0, stream>>>(W, Wq, (int)(wq_words / 2), 1);
        fpma_gemm_pre<<<grid, 256, 0, stream>>>(Xq, Wq, B, O, M, N, K);
    } else {
        fpma_gemm_fb<<<grid, 256, 0, stream>>>(X, W, B, O, M, N, K);
    }
}

// Round 12
// 506.193 us; speedup vs baseline: 2.2723x; 1.0007x over previous
//
#include <hip/hip_runtime.h>
#include <stdint.h>

typedef unsigned short v2u   __attribute__((ext_vector_type(2)));
typedef unsigned short u16x8 __attribute__((ext_vector_type(8)));
typedef short          s16x8 __attribute__((ext_vector_type(8)));
typedef float          f32x4 __attribute__((ext_vector_type(4)));

#define TM 64
#define TN 64

__device__ __forceinline__ uint32_t rnd_bf16(float f) {
    uint32_t u = __builtin_bit_cast(uint32_t, f);
    return (u + 0x7FFFu + ((u >> 16) & 1u)) >> 16;   // RNE f32 -> bf16 (finite)
}
__device__ __forceinline__ float bf16_to_f32(uint32_t bits16) {
    return __builtin_bit_cast(float, bits16 << 16);
}

// HW-validated pack transforms (r12/r15): mag floored at 0x2000;
// X side folds (sign - 0x3F80), W side keeps sign|mag.
__device__ __forceinline__ uint32_t pack_x(uint32_t w0, uint32_t w1) {
    uint32_t u = (w0 >> 16) | (w1 & 0xFFFF0000u);
    const v2u vfloor = {0x2000, 0x2000};
    v2u m = __builtin_bit_cast(v2u, u & 0x7FFF7FFFu);
    m = __builtin_elementwise_max(m, vfloor);
    uint32_t c = (u & 0x80008000u) ^ 0xC080C080u;    // sign - 0x3F80
    v2u xp = m + __builtin_bit_cast(v2u, c);
    return __builtin_bit_cast(uint32_t, xp);
}
__device__ __forceinline__ uint32_t pack_w(uint32_t w0, uint32_t w1) {
    uint32_t v = (w0 >> 16) | (w1 & 0xFFFF0000u);
    const v2u vfloor = {0x2000, 0x2000};
    v2u m = __builtin_bit_cast(v2u, v & 0x7FFF7FFFu);
    m = __builtin_elementwise_max(m, vfloor);
    return __builtin_bit_cast(uint32_t, m) | (v & 0x80008000u);
}

// Pre-pack pass: 4 raw f32-bit words -> 2 packed u32 (grid-stride, BW-bound).
__global__ void pack_kernel(const uint32_t* __restrict__ in,
                            uint32_t* __restrict__ out, int n4, int mode)
{
    int i = blockIdx.x * blockDim.x + threadIdx.x;
    const int stride = gridDim.x * blockDim.x;
    for (; i < n4; i += stride) {
        uint4 v = ((const uint4*)in)[i];
        uint2 o;
        if (mode == 0) { o.x = pack_x(v.x, v.y); o.y = pack_x(v.z, v.w); }
        else           { o.x = pack_w(v.x, v.y); o.y = pack_w(v.z, v.w); }
        ((uint2*)out)[i] = o;
    }
}

// ROUND 24. r23: 470-us GEMM dispatch, MfmaUtil 53.9%. Barrier-halving bought
// only 16 us -> barrier model DEAD. Lane-corrected pipe totals per CU: matrix
// 265 us floor, VALU-pk 109, LDS reads ~82 -> NO pipe saturated; matrix is
// starved 46% waiting on operands. Cause hypothesis: at launch_bounds(256,3)
// only ~20 spare regs -> compiler cannot keep ds_read fragments in flight;
// each (ks,bg) group stalls on lgkmcnt before its 32 MFMAs. (r16 2-blk 558 <
// r17 3-blk 570: per-wave ILP > TLP here.) This round: (a) bounds (256,2)
// for register headroom; (b) EXPLICIT fragment pipeline — while group g
// computes 32 MFMAs, issue group g+1's wf (and xf at ks boundary) reads.
// Accumulation order unchanged (ks->bg->t->a) -> bit-exact.
__global__ __launch_bounds__(256, 2)
void fpma_gemm_pre(const uint32_t* __restrict__ Xq,  // packed [M,K/2]
                   const uint32_t* __restrict__ Wq,  // packed [N,K/2]
                   const float*    __restrict__ Bias,// [N] f32 (bf16-exact)
                   float* __restrict__ Out,          // [M,N] f32 (bf16-valued)
                   int M, int N, int K)
{
    __shared__ uint32_t Xp[2][2][64 * 16];  // [buf][ksub][row*16], oct-swizzled
    __shared__ uint32_t Wp[2][2][64 * 16];

    const int tid  = threadIdx.x;
    const int lane = tid & 63;
    const int warp = tid >> 6;
    const int wm = warp >> 1, wn = warp & 1;
    const int m0 = blockIdx.y * TM;
    const int n0 = blockIdx.x * TN;

    // compute-side roles (r15/r16-validated A/D mapping)
    const int cc = lane & 15;
    const int q  = lane >> 4;            // k-octet within a 32-k sub-tile
    const int mi = cc >> 2;
    const int ni = cc & 3;

    const int xrd = (32 * wm + mi) * 16 + ((q ^ mi) << 2);
    int wrd[4];
    #pragma unroll
    for (int t = 0; t < 4; ++t)
        wrd[t] = (32 * wn + ni) * 16 + ((q ^ ni) << 2) + (((q + t) & 3) << 6);

    // B selectors: ones iff D col-group (cc>>2) == (q+t)&3
    u16x8 bt[4];
    #pragma unroll
    for (int t = 0; t < 4; ++t) {
        unsigned short v = ((cc >> 2) == ((q + t) & 3)) ? (unsigned short)0x3F80
                                                        : (unsigned short)0;
        bt[t] = (u16x8){v, v, v, v, v, v, v, v};
    }

    // staging roles: DMA dest linear tid*16B per sub-tile; swizzle moved to
    // the per-lane GLOBAL source octet (rule #21/m173; r22-validated).
    const int srow = tid >> 2;           // 0..63
    const int soct = tid & 3;            // 0..3
    const int Kp = K >> 1;               // packed words per row
    const int swz = (soct ^ (srow & 3)) << 2;
    const uint32_t* xsrc = Xq + (size_t)(m0 + srow) * Kp + swz;
    const uint32_t* wsrc = Wq + (size_t)(n0 + srow) * Kp + swz;

    f32x4 acc[8][2];
    #pragma unroll
    for (int a = 0; a < 8; ++a)
        #pragma unroll
        for (int bg = 0; bg < 2; ++bg) acc[a][bg] = (f32x4){0.f, 0.f, 0.f, 0.f};

    // prologue: DMA chunk 0 (both 32-k sub-tiles) into buf 0
    __builtin_amdgcn_global_load_lds(xsrc,      &Xp[0][0][tid << 2], 16, 0, 0);
    __builtin_amdgcn_global_load_lds(xsrc + 16, &Xp[0][1][tid << 2], 16, 0, 0);
    __builtin_amdgcn_global_load_lds(wsrc,      &Wp[0][0][tid << 2], 16, 0, 0);
    __builtin_amdgcn_global_load_lds(wsrc + 16, &Wp[0][1][tid << 2], 16, 0, 0);
    xsrc += 32; wsrc += 32;
    __syncthreads();   // drain: chunk-0 staging visible

    const int ksteps = K / 64;
    #pragma unroll 1
    for (int kt = 0; kt < ksteps; ++kt) {
        const int cur = kt & 1;
        if (kt + 1 < ksteps) {
            __builtin_amdgcn_global_load_lds(xsrc,      &Xp[cur ^ 1][0][tid << 2], 16, 0, 0);
            __builtin_amdgcn_global_load_lds(xsrc + 16, &Xp[cur ^ 1][1][tid << 2], 16, 0, 0);
            __builtin_amdgcn_global_load_lds(wsrc,      &Wp[cur ^ 1][0][tid << 2], 16, 0, 0);
            __builtin_amdgcn_global_load_lds(wsrc + 16, &Wp[cur ^ 1][1][tid << 2], 16, 0, 0);
            xsrc += 32; wsrc += 32;
        }

        // explicit fragment pipeline over groups g = (ks,bg) = 00,01,10,11
        u16x8 xf[8], xfn[8], wf[4], wfn[4];
        #pragma unroll
        for (int a = 0; a < 8; ++a)
            xf[a] = __builtin_bit_cast(u16x8,
                        *(const uint4*)&Xp[cur][0][xrd + a * 64]);
        #pragma unroll
        for (int t = 0; t < 4; ++t)
            wf[t] = __builtin_bit_cast(u16x8,
                        *(const uint4*)&Wp[cur][0][wrd[t]]);

        __builtin_amdgcn_s_setprio(1);
        #pragma unroll
        for (int g = 0; g < 4; ++g) {
            const int bg = g & 1;
            // issue next group's reads BEFORE computing current group
            if (g < 3) {
                const int nks = (g + 1) >> 1, nbg = (g + 1) & 1;
                #pragma unroll
                for (int t = 0; t < 4; ++t)
                    wfn[t] = __builtin_bit_cast(u16x8,
                                 *(const uint4*)&Wp[cur][nks][wrd[t] + nbg * 256]);
                if (nks != (g >> 1)) {
                    #pragma unroll
                    for (int a = 0; a < 8; ++a)
                        xfn[a] = __builtin_bit_cast(u16x8,
                                     *(const uint4*)&Xp[cur][nks][xrd + a * 64]);
                }
            }
            // compute current group: 4t x 8a = 32 MFMAs
            #pragma unroll
            for (int t = 0; t < 4; ++t)
                #pragma unroll
                for (int a = 0; a < 8; ++a) {
                    u16x8 p = xf[a] + wf[t];           // 4x v_pk_add_u16
                    if (bg == 0)
                        acc[a][0] = __builtin_amdgcn_mfma_f32_16x16x32_bf16(
                            __builtin_bit_cast(s16x8, p),
                            __builtin_bit_cast(s16x8, bt[t]), acc[a][0], 0, 0, 0);
                    else
                        acc[a][1] = __builtin_amdgcn_mfma_f32_16x16x32_bf16(
                            __builtin_bit_cast(s16x8, p),
                            __builtin_bit_cast(s16x8, bt[t]), acc[a][1], 0, 0, 0);
                }
            // rotate pipelined fragments
            if (g < 3) {
                #pragma unroll
                for (int t = 0; t < 4; ++t) wf[t] = wfn[t];
                if (((g + 1) >> 1) != (g >> 1)) {
                    #pragma unroll
                    for (int a = 0; a < 8; ++a) xf[a] = xfn[a];
                }
            }
        }
        __builtin_amdgcn_s_setprio(0);
        __syncthreads();   // drains DMA into cur^1 + lgkm; publishes
    }

    // Epilogue (r16-validated). acc[a][bg]: lane (cc,q), elem j =
    // out(m0+32wm+4a+q, n0+32wn+16bg+4*(cc>>2)+j); lane stores a's with
    // a&3 == cc&3 (disjoint, complete cover of 64x64 tile).
    const int g = cc >> 2;
    f32x4 bias_[2];
    #pragma unroll
    for (int bg = 0; bg < 2; ++bg)
        bias_[bg] = *(const f32x4*)&Bias[n0 + 32 * wn + 16 * bg + 4 * g];

    #pragma unroll
    for (int a = 0; a < 8; ++a) {
        if ((cc & 3) == (a & 3)) {
            #pragma unroll
            for (int bg = 0; bg < 2; ++bg) {
                float o[4];
                #pragma unroll
                for (int j = 0; j < 4; ++j)
                    o[j] = bf16_to_f32(rnd_bf16(
                               bf16_to_f32(rnd_bf16(acc[a][bg][j])) + bias_[bg][j]));
                const size_t row = (size_t)(m0 + 32 * wm + 4 * a + q) * N;
                *(float4*)&Out[row + n0 + 32 * wn + 16 * bg + 4 * g] =
                    make_float4(o[0], o[1], o[2], o[3]);
            }
        }
    }
}

// Fallback (ws too small): r16 path — in-kernel pack, BK=32, reg prefetch.
__global__ __launch_bounds__(256, 3)
void fpma_gemm_fb(const uint32_t* __restrict__ X, const uint32_t* __restrict__ Wt,
                  const float* __restrict__ Bias, float* __restrict__ Out,
                  int M, int N, int K)
{
    __shared__ uint32_t Xp[2][64 * 16];
    __shared__ uint32_t Wp[2][64 * 16];

    const int tid  = threadIdx.x;
    const int lane = tid & 63;
    const int warp = tid >> 6;
    const int wm = warp >> 1, wn = warp & 1;
    const int m0 = blockIdx.y * TM;
    const int n0 = blockIdx.x * TN;
    const int cc = lane & 15;
    const int q  = lane >> 4;
    const int mi = cc >> 2;
    const int ni = cc & 3;
    const int xrd = (32 * wm + mi) * 16 + ((q ^ mi) << 2);
    int wrd[4];
    #pragma unroll
    for (int t = 0; t < 4; ++t)
        wrd[t] = (32 * wn + ni) * 16 + ((q ^ ni) << 2) + (((q + t) & 3) << 6);
    u16x8 bt[4];
    #pragma unroll
    for (int t = 0; t < 4; ++t) {
        unsigned short v = ((cc >> 2) == ((q + t) & 3)) ? (unsigned short)0x3F80
                                                        : (unsigned short)0;
        bt[t] = (u16x8){v, v, v, v, v, v, v, v};
    }
    const int srow = tid >> 2;
    const int soct = tid & 3;
    const uint32_t* xptr = X  + (size_t)(m0 + srow) * K + soct * 8;
    const uint32_t* wptr = Wt + (size_t)(n0 + srow) * K + soct * 8;
    const int st = srow * 16 + ((soct ^ (srow & 3)) << 2);

    f32x4 acc[8][2];
    #pragma unroll
    for (int a = 0; a < 8; ++a)
        #pragma unroll
        for (int bg = 0; bg < 2; ++bg) acc[a][bg] = (f32x4){0.f, 0.f, 0.f, 0.f};

    {
        uint4 a0 = *(const uint4*)(xptr), a1 = *(const uint4*)(xptr + 4);
        uint4 b0 = *(const uint4*)(wptr), b1 = *(const uint4*)(wptr + 4);
        *(uint4*)&Xp[0][st] = (uint4){pack_x(a0.x,a0.y), pack_x(a0.z,a0.w),
                                      pack_x(a1.x,a1.y), pack_x(a1.z,a1.w)};
        *(uint4*)&Wp[0][st] = (uint4){pack_w(b0.x,b0.y), pack_w(b0.z,b0.w),
                                      pack_w(b1.x,b1.y), pack_w(b1.z,b1.w)};
    }
    uint4 gx0 = {0,0,0,0}, gx1 = {0,0,0,0}, gw0 = {0,0,0,0}, gw1 = {0,0,0,0};
    const int ksteps = K / 32;
    if (ksteps > 1) {
        xptr += 32; wptr += 32;
        gx0 = *(const uint4*)(xptr); gx1 = *(const uint4*)(xptr + 4);
        gw0 = *(const uint4*)(wptr); gw1 = *(const uint4*)(wptr + 4);
    }
    __syncthreads();

    #pragma unroll 1
    for (int kt = 0; kt < ksteps; ++kt) {
        const int cur = kt & 1;
        if (kt + 1 < ksteps) {
            *(uint4*)&Xp[cur ^ 1][st] = (uint4){pack_x(gx0.x,gx0.y), pack_x(gx0.z,gx0.w),
                                                pack_x(gx1.x,gx1.y), pack_x(gx1.z,gx1.w)};
            *(uint4*)&Wp[cur ^ 1][st] = (uint4){pack_w(gw0.x,gw0.y), pack_w(gw0.z,gw0.w),
                                                pack_w(gw1.x,gw1.y), pack_w(gw1.z,gw1.w)};
            if (kt + 2 < ksteps) {
                xptr += 32; wptr += 32;
                gx0 = *(const uint4*)(xptr); gx1 = *(const uint4*)(xptr + 4);
                gw0 = *(const uint4*)(wptr); gw1 = *(const uint4*)(wptr + 4);
            }
        }
        u16x8 xf[8];
        #pragma unroll
        for (int a = 0; a < 8; ++a)
            xf[a] = __builtin_bit_cast(u16x8, *(const uint4*)&Xp[cur][xrd + a * 64]);
        #pragma unroll
        for (int bg = 0; bg < 2; ++bg) {
            u16x8 wf[4];
            #pragma unroll
            for (int t = 0; t < 4; ++t)
                wf[t] = __builtin_bit_cast(u16x8, *(const uint4*)&Wp[cur][wrd[t] + bg * 256]);
            #pragma unroll
            for (int t = 0; t < 4; ++t)
                #pragma unroll
                for (int a = 0; a < 8; ++a) {
                    u16x8 p = xf[a] + wf[t];
                    acc[a][bg] = __builtin_amdgcn_mfma_f32_16x16x32_bf16(
                        __builtin_bit_cast(s16x8, p),
                        __builtin_bit_cast(s16x8, bt[t]), acc[a][bg], 0, 0, 0);
                }
        }
        __syncthreads();
    }

    const int g = cc >> 2;
    f32x4 bias_[2];
    #pragma unroll
    for (int bg = 0; bg < 2; ++bg)
        bias_[bg] = *(const f32x4*)&Bias[n0 + 32 * wn + 16 * bg + 4 * g];
    #pragma unroll
    for (int a = 0; a < 8; ++a) {
        if ((cc & 3) == (a & 3)) {
            #pragma unroll
            for (int bg = 0; bg < 2; ++bg) {
                float o[4];
                #pragma unroll
                for (int j = 0; j < 4; ++j)
                    o[j] = bf16_to_f32(rnd_bf16(
                               bf16_to_f32(rnd_bf16(acc[a][bg][j])) + bias_[bg][j]));
                const size_t row = (size_t)(m0 + 32 * wm + 4 * a + q) * N;
                *(float4*)&Out[row + n0 + 32 * wn + 16 * bg + 4 * g] =
                    make_float4(o[0], o[1], o[2], o[3]);
            }
        }
    }
}

extern "C" void kernel_launch(void* const* d_in, const int* in_sizes, int n_in,
                              void* d_out, int out_size, void* d_ws, size_t ws_size,
                              hipStream_t stream) {
    (void)n_in; (void)out_size;
    const uint32_t* X = (const uint32_t*)d_in[0];   // f32 words (bf16-exact)
    const uint32_t* W = (const uint32_t*)d_in[1];
    const float*    B = (const float*)d_in[2];
    float* O = (float*)d_out;                       // f32 out (bf16-valued)

    int N = in_sizes[2];                       // bias [1,N], elements
    int K = (N > 0) ? in_sizes[1] / N : 0;     // weight [N,K]
    int M = (K > 0) ? in_sizes[0] / K : 0;     // input [M,K]
    if (N <= 0 || K <= 0 || M <= 0 ||
        (long long)N * K != (long long)in_sizes[1] ||
        (long long)M * K != (long long)in_sizes[0] ||
        (M % TM) || (N % TN) || (K % 64)) {
        M = 4096; K = 2048; N = 2048;          // documented problem shape
    }

    const size_t xq_words = (size_t)M * (K / 2);
    const size_t wq_words = (size_t)N * (K / 2);
    const size_t need = (xq_words + wq_words) * 4;

    dim3 grid(N / TN, M / TM);
    if (d_ws != nullptr && ws_size >= need) {
        uint32_t* Xq = (uint32_t*)d_ws;
        uint32_t* Wq = Xq + xq_words;
        pack_kernel<<<1024, 256, 0, stream>>>(X, Xq, (int)(xq_words / 2), 0);
        pack_kernel<<<1024, 256, 0, stream>>>(W, Wq, (int)(wq_words / 2), 1);
        fpma_gemm_pre<<<grid, 256, 0, stream>>>(Xq, Wq, B, O, M, N, K);
    } else {
        fpma_gemm_fb<<<grid, 256, 0, stream>>>(X, W, B, O, M, N, K);
    }
}